// Round 17
// baseline (638.527 us; speedup 1.0000x reference)
//
#include <hip/hip_runtime.h>

// SBMAttention — round 17: full-row streaming kSample.
// r16 validated the f32+margin+f64-fallback sampling path (identical bits).
// r16 also falsified "kSample is f64-VALU-bound". New theory: kSample's 2KB-
// per-8KB-stride chunks run at ~2.5 TB/s; fillBuffer proves contiguous streams
// hit 6.7 TB/s at <1 wave/SIMD. This kSample gives each block a contiguous
// 512KB noise/graph region (64 full rows), thread owns 8 columns with sktf
// rows in 128 f32 VGPRs. Everything else = r15/r16 best (480µs config).

typedef float  f32x4 __attribute__((ext_vector_type(4)));
typedef float  f32x8 __attribute__((ext_vector_type(8)));
typedef double f64x2 __attribute__((ext_vector_type(2)));
typedef __bf16 bf16x8 __attribute__((ext_vector_type(8)));

__device__ __forceinline__ unsigned short f2bf(float f) {
  __bf16 b = (__bf16)f;
  return __builtin_bit_cast(unsigned short, b);
}
__device__ __forceinline__ float bf2f(unsigned short u) {
  return (float)__builtin_bit_cast(__bf16, u);
}

// ---------------- kS: cluster softmax (f64) — validated ----------------
__global__ __launch_bounds__(256) void kS(const float* __restrict__ emb,
                                          double* __restrict__ wsS,
                                          float* __restrict__ wsSP) {
  __shared__ double c[16][65];
  __shared__ double red[256];
  const int t = threadIdx.x, h = blockIdx.x;
  if (t == 0) wsSP[h] = 0.f;
  for (int i = t; i < 1024; i += 256) c[i >> 6][i & 63] = (double)emb[(size_t)h * 1024 + i];
  __syncthreads();
  const int k = t >> 4, j = t & 15;
  double acc = 0.0;
  for (int d = 0; d < 64; ++d) acc += c[k][d] * c[j][d];
  red[t] = acc; __syncthreads();
  for (int s = 128; s > 0; s >>= 1) { if (t < s) red[t] = fmax(red[t], red[t + s]); __syncthreads(); }
  const double mx = red[0]; __syncthreads();
  const double e = exp(acc - mx);
  red[t] = e; __syncthreads();
  for (int s = 128; s > 0; s >>= 1) { if (t < s) red[t] += red[t + s]; __syncthreads(); }
  wsS[h * 256 + t] = e / red[0];
}

// ---------------- kMLP: proj + hats (f64) + f32 copies (r16) ----------------
__global__ __launch_bounds__(256) void kMLP(
    const float* __restrict__ Q, const float* __restrict__ K,
    const float* __restrict__ emb,
    const float* __restrict__ W1, const float* __restrict__ b1,
    const float* __restrict__ W2, const float* __restrict__ b2,
    const float* __restrict__ W3, const float* __restrict__ b3,
    const double* __restrict__ wsS,
    double* __restrict__ QHAT, double* __restrict__ SKT,
    float* __restrict__ QHATF, float* __restrict__ SKTF) {
  __shared__ double Xt[64][66];
  __shared__ float  Wl[64][68];
  __shared__ float  bsS[64];
  __shared__ float  cl[16][68];
  __shared__ double kh[64][17];
  __shared__ double Sl[256];

  const int t = threadIdx.x;
  const int blk = blockIdx.x;
  const int side = blk >> 9;
  const int idx = blk & 511;
  const int bh = idx >> 5;
  const int h = bh & 7;
  const int chunk = idx & 31;
  const size_t t0 = (size_t)bh * 2048 + (size_t)chunk * 64;

  const float* src = side ? K : Q;
  for (int i = t; i < 4096; i += 256) Xt[i >> 6][i & 63] = (double)src[t0 * 64 + i];

  const float* Ws[3] = {W1, W2, W3};
  const float* bs[3] = {b1, b2, b3};
  const int te = t & 15, tt = t >> 4;
  const int e0 = te * 4, tok0 = tt * 4;

  for (int l = 0; l < 3; ++l) {
    __syncthreads();
    for (int i = t; i < 4096; i += 256) Wl[i >> 6][i & 63] = Ws[l][i];
    if (t < 64) bsS[t] = bs[l][t];
    __syncthreads();
    double o[4][4];
#pragma unroll
    for (int i = 0; i < 4; ++i)
#pragma unroll
      for (int j = 0; j < 4; ++j) o[i][j] = 0.0;
    for (int d = 0; d < 64; d += 4) {
      double xa[4][4];
#pragma unroll
      for (int i = 0; i < 4; ++i) {
        const f64x2 lo = *(const f64x2*)&Xt[tok0 + i][d];
        const f64x2 hi = *(const f64x2*)&Xt[tok0 + i][d + 2];
        xa[i][0] = lo[0]; xa[i][1] = lo[1]; xa[i][2] = hi[0]; xa[i][3] = hi[1];
      }
      float4 wb[4];
#pragma unroll
      for (int j = 0; j < 4; ++j) wb[j] = *(const float4*)&Wl[e0 + j][d];
#pragma unroll
      for (int dd = 0; dd < 4; ++dd) {     // d ascending: FMA order preserved
        const double w0 = (double)((dd == 0) ? wb[0].x : (dd == 1) ? wb[0].y : (dd == 2) ? wb[0].z : wb[0].w);
        const double w1 = (double)((dd == 0) ? wb[1].x : (dd == 1) ? wb[1].y : (dd == 2) ? wb[1].z : wb[1].w);
        const double w2 = (double)((dd == 0) ? wb[2].x : (dd == 1) ? wb[2].y : (dd == 2) ? wb[2].z : wb[2].w);
        const double w3 = (double)((dd == 0) ? wb[3].x : (dd == 1) ? wb[3].y : (dd == 2) ? wb[3].z : wb[3].w);
#pragma unroll
        for (int i = 0; i < 4; ++i) {
          const double xv = xa[i][dd];
          o[i][0] += xv * w0; o[i][1] += xv * w1; o[i][2] += xv * w2; o[i][3] += xv * w3;
        }
      }
    }
#pragma unroll
    for (int i = 0; i < 4; ++i)
#pragma unroll
      for (int j = 0; j < 4; ++j) {
        double v = o[i][j] + (double)bsS[e0 + j];
        if (l < 2) v = fmax(v, 0.0);
        o[i][j] = v;
      }
    __syncthreads();
#pragma unroll
    for (int i = 0; i < 4; ++i)
#pragma unroll
      for (int j = 0; j < 4; ++j) Xt[tok0 + i][e0 + j] = o[i][j];
  }
  __syncthreads();
  for (int i = t; i < 1024; i += 256) cl[i >> 6][i & 63] = emb[(size_t)h * 1024 + i];
  if (side) { for (int i = t; i < 256; i += 256) Sl[i] = wsS[h * 256 + i]; }
  __syncthreads();

  const int tok = t >> 2, k0 = (t & 3) * 4;
  double z[4] = {0.0, 0.0, 0.0, 0.0};
  for (int d = 0; d < 64; d += 2) {
    const f64x2 xv = *(const f64x2*)&Xt[tok][d];
    const float2 c0 = *(const float2*)&cl[k0 + 0][d];
    const float2 c1 = *(const float2*)&cl[k0 + 1][d];
    const float2 c2 = *(const float2*)&cl[k0 + 2][d];
    const float2 c3 = *(const float2*)&cl[k0 + 3][d];
    z[0] += xv[0] * (double)c0.x; z[1] += xv[0] * (double)c1.x;
    z[2] += xv[0] * (double)c2.x; z[3] += xv[0] * (double)c3.x;
    z[0] += xv[1] * (double)c0.y; z[1] += xv[1] * (double)c1.y;
    z[2] += xv[1] * (double)c2.y; z[3] += xv[1] * (double)c3.y;
  }
  double hat[4];
#pragma unroll
  for (int j = 0; j < 4; ++j) hat[j] = 1.0 / (1.0 + exp(-z[j]));

  if (!side) {
#pragma unroll
    for (int j = 0; j < 4; ++j) {
      QHAT[(t0 + tok) * 16 + k0 + j] = hat[j];
      QHATF[(t0 + tok) * 16 + k0 + j] = (float)hat[j];
    }
  } else {
    kh[tok][k0 + 0] = hat[0]; kh[tok][k0 + 1] = hat[1];
    kh[tok][k0 + 2] = hat[2]; kh[tok][k0 + 3] = hat[3];
    __syncthreads();
    double sk[4] = {0.0, 0.0, 0.0, 0.0};
    for (int jj = 0; jj < 16; ++jj) {
      const double kv = kh[tok][jj];
      sk[0] += Sl[(k0 + 0) * 16 + jj] * kv; sk[1] += Sl[(k0 + 1) * 16 + jj] * kv;
      sk[2] += Sl[(k0 + 2) * 16 + jj] * kv; sk[3] += Sl[(k0 + 3) * 16 + jj] * kv;
    }
#pragma unroll
    for (int j = 0; j < 4; ++j) {
      SKT[(t0 + tok) * 16 + k0 + j] = sk[j];
      SKTF[(t0 + tok) * 16 + k0 + j] = (float)sk[j];
    }
  }
}

// ---------------- kSample: full-row streaming, f32 fast path ----------------
// grid (32, 16): x = 64-row tile, y = bh. Block covers ALL 2048 columns:
// thread t owns columns j*256+t (j=0..7), sktf rows in 128 f32 regs.
// Per row: one contiguous 8KB noise read + 8KB graph write (pure streams).
__global__ __launch_bounds__(256, 2) void kSample(
    const float* __restrict__ noise,
    const double* __restrict__ qhat, const double* __restrict__ skt,
    const float* __restrict__ qhatf, const float* __restrict__ sktf,
    float* __restrict__ wsSP,
    unsigned long long* __restrict__ GB64, float* __restrict__ GOUT) {
  const int t = threadIdx.x;
  const int lane = t & 63, wave = t >> 6;
  const int bh = blockIdx.y, h = bh & 7;
  const int n0 = blockIdx.x * 64;

  float skv[8][16];   // 128 VGPR: this thread's 8 sktf rows
#pragma unroll
  for (int j = 0; j < 8; ++j) {
    const float* sp = sktf + ((size_t)bh * 2048 + j * 256 + t) * 16;
#pragma unroll
    for (int q = 0; q < 4; ++q) *(f32x4*)(skv[j] + 4 * q) = *(const f32x4*)(sp + 4 * q);
  }

  const float* qbaseF = qhatf + ((size_t)bh * 2048 + n0) * 16;   // wave-uniform
  const double* qbase64 = qhat + ((size_t)bh * 2048 + n0) * 16;  // rare fallback
  const double* skbase64 = skt + (size_t)bh * 2048 * 16;
  const float* nzbase = noise + ((size_t)bh * 2048 + n0) * 2048;
  float* gobase = GOUT + ((size_t)bh * 2048 + n0) * 2048;
  unsigned long long* gbbase = GB64 + ((size_t)bh * 2048 + n0) * 32;

  int cnt = 0;
  for (int n = 0; n < 64; ++n) {
    const float* qr = qbaseF + (size_t)n * 16;   // uniform -> scalar loads
    const float* nzrow = nzbase + (size_t)n * 2048;
    float* gorow = gobase + (size_t)n * 2048;
    unsigned long long* gbrow = gbbase + (size_t)n * 32;
#pragma unroll
    for (int j = 0; j < 8; ++j) {
      const float nz = nzrow[j * 256 + t];
      float ea = 0.f;
#pragma unroll
      for (int k = 0; k < 16; ++k) ea = fmaf(qr[k], skv[j][k], ea);
      int g;
      if (__builtin_expect(fabsf(nz - ea) < 1e-5f, 0)) {   // borderline: exact
        const double* q64 = qbase64 + (size_t)n * 16;
        const double* s64 = skbase64 + (size_t)(j * 256 + t) * 16;
        double e = 0.0;
        for (int k = 0; k < 16; ++k) e += q64[k] * s64[k];  // np order
        g = ((double)nz < e) ? 1 : 0;
      } else {
        g = (nz < ea) ? 1 : 0;
      }
      cnt += g;
      const unsigned long long bb = __ballot(g);   // lanes hold consecutive m
      if (lane == 0) gbrow[j * 4 + wave] = bb;
      gorow[j * 256 + t] = g ? 1.0f : 0.0f;
    }
  }
  cnt += __shfl_xor(cnt, 1); cnt += __shfl_xor(cnt, 2); cnt += __shfl_xor(cnt, 4);
  cnt += __shfl_xor(cnt, 8); cnt += __shfl_xor(cnt, 16); cnt += __shfl_xor(cnt, 32);
  if (lane == 0) atomicAdd(&wsSP[h], (float)cnt);
}

// ---------------- kCvt: K->bf16 KB, V->bf16 transposed VT ----------------
__global__ __launch_bounds__(256) void kCvt(const float* __restrict__ K,
                                            const float* __restrict__ V,
                                            unsigned short* __restrict__ KB,
                                            unsigned short* __restrict__ VT) {
  __shared__ float vt[128][65];
  const int t = threadIdx.x;
  const int bh = blockIdx.x, ch = blockIdx.y;
  const size_t base = ((size_t)bh * 2048 + ch * 128) * 64;
  for (int i = t; i < 8192; i += 256) {
    KB[base + i] = f2bf(K[base + i]);
    vt[i >> 6][i & 63] = V[base + i];
  }
  __syncthreads();
  const size_t vbase = (size_t)bh * 64 * 2048 + ch * 128;
  for (int i = t; i < 8192; i += 256) {
    const int d = i >> 7, mm = i & 127;
    VT[vbase + (size_t)d * 2048 + mm] = f2bf(vt[mm][d]);
  }
}

// ---------------- kAttn: two-phase MFMA attention, 32-row Q-tiles (r15) -----
__global__ __launch_bounds__(256, 4) void kAttn(
    const float* __restrict__ Q, const int* __restrict__ maskp,
    const unsigned short* __restrict__ KB, const unsigned short* __restrict__ VT,
    const unsigned int* __restrict__ GB32,
    float* __restrict__ XOUT, float* __restrict__ AOUT) {
  __shared__ unsigned int bitsS[32][64];
  __shared__ unsigned short stageS[4][32][32];
  __shared__ float dredS[4][32];
  __shared__ float dinvS[32];
  __shared__ float xredS[32][68];

  const int t = threadIdx.x;
  const int wave = t >> 6, lane = t & 63;
  const int bh = blockIdx.y, b = bh >> 3;
  const int n0 = blockIdx.x * 32;
  const int hi2 = lane >> 4;
  const int hi8 = hi2 << 3;
  const int g4 = hi2 << 2;
  const int lm = lane & 15;

  for (int i = t; i < 2048; i += 256)
    bitsS[i >> 6][i & 63] = GB32[((size_t)bh * 2048 + n0 + (i >> 6)) * 64 + (i & 63)];
  for (int i = t; i < 32 * 68; i += 256) ((float*)xredS)[i] = 0.f;

  bf16x8 aq[2][2];
#pragma unroll
  for (int rs = 0; rs < 2; ++rs) {
    const float* qrow = Q + ((size_t)bh * 2048 + n0 + rs * 16 + lm) * 64;
#pragma unroll
    for (int hh = 0; hh < 2; ++hh) {
      const int d0 = hi8 + hh * 32;
      const f32x4 qa = *(const f32x4*)(qrow + d0);
      const f32x4 qb = *(const f32x4*)(qrow + d0 + 4);
      bf16x8 v;
      v[0] = (__bf16)qa[0]; v[1] = (__bf16)qa[1]; v[2] = (__bf16)qa[2]; v[3] = (__bf16)qa[3];
      v[4] = (__bf16)qb[0]; v[5] = (__bf16)qb[1]; v[6] = (__bf16)qb[2]; v[7] = (__bf16)qb[3];
      aq[rs][hh] = v;
    }
  }

  const unsigned short* kbp = KB + (size_t)bh * 2048 * 64;
  const unsigned short* vtp = VT + (size_t)bh * 64 * 2048;
  const int* mkp = maskp + b * 2048;
  __syncthreads();

  // PHASE 1: denominators
  float dsum[2][4];
#pragma unroll
  for (int rs = 0; rs < 2; ++rs)
#pragma unroll
    for (int r = 0; r < 4; ++r) dsum[rs][r] = 0.f;

  for (int it = 0; it < 16; ++it) {
    const int mb = (wave << 9) + (it << 5);
    f32x4 st[2][2];
#pragma unroll
    for (int tt = 0; tt < 2; ++tt) {
      const unsigned short* kr = kbp + (size_t)(mb + tt * 16 + lm) * 64 + hi8;
      const bf16x8 b0 = *(const bf16x8*)(kr);
      const bf16x8 b1 = *(const bf16x8*)(kr + 32);
#pragma unroll
      for (int rs = 0; rs < 2; ++rs) {
        f32x4 acc = (f32x4){0.f, 0.f, 0.f, 0.f};
        acc = __builtin_amdgcn_mfma_f32_16x16x32_bf16(aq[rs][0], b0, acc, 0, 0, 0);
        acc = __builtin_amdgcn_mfma_f32_16x16x32_bf16(aq[rs][1], b1, acc, 0, 0, 0);
        st[rs][tt] = acc;
      }
    }
#pragma unroll
    for (int tt = 0; tt < 2; ++tt) {
      const int mv = mkp[mb + tt * 16 + lm];
#pragma unroll
      for (int rs = 0; rs < 2; ++rs) {
        const f32x4 sv4 = st[rs][tt];
#pragma unroll
        for (int r = 0; r < 4; ++r) {
          const int g = (bitsS[rs * 16 + g4 + r][mb >> 5] >> (tt * 16 + lm)) & 1;
          if (g && !mv) dsum[rs][r] += __expf(sv4[r] * 0.125f);
        }
      }
    }
  }
#pragma unroll
  for (int rs = 0; rs < 2; ++rs)
#pragma unroll
    for (int r = 0; r < 4; ++r) {
      float v = dsum[rs][r];
      v += __shfl_xor(v, 1); v += __shfl_xor(v, 2); v += __shfl_xor(v, 4); v += __shfl_xor(v, 8);
      if (lm == 0) dredS[wave][rs * 16 + g4 + r] = v;
    }
  __syncthreads();
  if (t < 32) {
    const float dv = dredS[0][t] + dredS[1][t] + dredS[2][t] + dredS[3][t];
    dinvS[t] = 1.0f / fmaxf(dv, 1e-12f);
  }
  __syncthreads();

  // PHASE 2: u rebuild, PV, attn writes
  const size_t rowbase = (size_t)bh * 2048 + n0;
  f32x4 xacc[2][4];
#pragma unroll
  for (int rs = 0; rs < 2; ++rs)
#pragma unroll
    for (int td = 0; td < 4; ++td) xacc[rs][td] = (f32x4){0.f, 0.f, 0.f, 0.f};

  for (int it = 0; it < 16; ++it) {
    const int mb = (wave << 9) + (it << 5);
    f32x4 st[2][2];
#pragma unroll
    for (int tt = 0; tt < 2; ++tt) {
      const unsigned short* kr = kbp + (size_t)(mb + tt * 16 + lm) * 64 + hi8;
      const bf16x8 b0 = *(const bf16x8*)(kr);
      const bf16x8 b1 = *(const bf16x8*)(kr + 32);
#pragma unroll
      for (int rs = 0; rs < 2; ++rs) {
        f32x4 acc = (f32x4){0.f, 0.f, 0.f, 0.f};
        acc = __builtin_amdgcn_mfma_f32_16x16x32_bf16(aq[rs][0], b0, acc, 0, 0, 0);
        acc = __builtin_amdgcn_mfma_f32_16x16x32_bf16(aq[rs][1], b1, acc, 0, 0, 0);
        st[rs][tt] = acc;
      }
    }
#pragma unroll
    for (int tt = 0; tt < 2; ++tt) {
      const int mv = mkp[mb + tt * 16 + lm];
#pragma unroll
      for (int rs = 0; rs < 2; ++rs) {
        const f32x4 sv4 = st[rs][tt];
#pragma unroll
        for (int r = 0; r < 4; ++r) {
          const int row = rs * 16 + g4 + r;
          const int g = (bitsS[row][mb >> 5] >> (tt * 16 + lm)) & 1;
          const float u = (g && !mv) ? __expf(sv4[r] * 0.125f) : 0.f;
          const int col = tt * 16 + lm;
          stageS[wave][row][col ^ (((row >> 2) & 3) << 3)] = f2bf(u);
        }
      }
    }
    {
      const int rdcol = hi8 ^ (((lm >> 2) & 3) << 3);
      const bf16x8 ua0 = *(const bf16x8*)&stageS[wave][lm][rdcol];
      const bf16x8 ua1 = *(const bf16x8*)&stageS[wave][16 + lm][rdcol];
#pragma unroll
      for (int td = 0; td < 4; ++td) {
        const bf16x8 vb = *(const bf16x8*)(vtp + (size_t)(td * 16 + lm) * 2048 + mb + hi8);
        xacc[0][td] = __builtin_amdgcn_mfma_f32_16x16x32_bf16(ua0, vb, xacc[0][td], 0, 0, 0);
        xacc[1][td] = __builtin_amdgcn_mfma_f32_16x16x32_bf16(ua1, vb, xacc[1][td], 0, 0, 0);
      }
    }
#pragma unroll
    for (int rs = 0; rs < 2; ++rs) {
      const int row4 = lane >> 2, q = lane & 3;
      const int row = rs * 16 + row4;
      const int rc = (q * 8) ^ (((row4 >> 2) & 3) << 3);
      const unsigned short* up = &stageS[wave][row][rc];
      const float inv = dinvS[row];
      f32x8 av;
#pragma unroll
      for (int j = 0; j < 8; ++j) av[j] = bf2f(up[j]) * inv;
      *(f32x8*)(AOUT + (rowbase + row) * 2048 + mb + q * 8) = av;
    }
  }

  for (int w = 0; w < 4; ++w) {
    if (wave == w) {
#pragma unroll
      for (int rs = 0; rs < 2; ++rs)
#pragma unroll
        for (int td = 0; td < 4; ++td)
#pragma unroll
          for (int r = 0; r < 4; ++r)
            xredS[rs * 16 + g4 + r][td * 16 + lm] += xacc[rs][td][r];
    }
    __syncthreads();
  }
  for (int i = t; i < 2048; i += 256) {
    const int nl = i >> 6, d = i & 63;
    XOUT[(rowbase + nl) * 64 + d] = xredS[nl][d] * dinvS[nl];
  }
}

// ---------------- kFin: sparsity (f32) ----------------
__global__ void kFin(const float* __restrict__ wsSP, float* __restrict__ SPOUT) {
  const int t = threadIdx.x;
  if (t < 8) SPOUT[t] = wsSP[t] * (1.0f / 8388608.0f);  // /(2*2048*2048)
}

extern "C" void kernel_launch(void* const* d_in, const int* in_sizes, int n_in,
                              void* d_out, int out_size, void* d_ws, size_t ws_size,
                              hipStream_t stream) {
  const float* Q = (const float*)d_in[0];
  const float* K = (const float*)d_in[1];
  const float* V = (const float*)d_in[2];
  const int* mask = (const int*)d_in[3];
  const float* noise = (const float*)d_in[4];
  const float* emb = (const float*)d_in[5];
  const float* W1 = (const float*)d_in[6];
  const float* b1 = (const float*)d_in[7];
  const float* W2 = (const float*)d_in[8];
  const float* b2 = (const float*)d_in[9];
  const float* W3 = (const float*)d_in[10];
  const float* b3 = (const float*)d_in[11];

  char* ws = (char*)d_ws;
  double* wsS = (double*)(ws + 0);                          // 16 KB
  float* wsSP = (float*)(ws + 16384);                       // 8 f32
  double* QHAT = (double*)(ws + 32768);                     // 4 MB f64
  double* SKT  = (double*)(ws + 32768 + 4194304);           // 4 MB f64
  unsigned short* KB = (unsigned short*)(ws + 32768);             // 4 MB bf16
  unsigned short* VT = (unsigned short*)(ws + 32768 + 4194304);   // 4 MB bf16
  unsigned long long* GB64 = (unsigned long long*)(ws + 32768 + 8388608);  // 8 MB
  unsigned int* GB32 = (unsigned int*)(ws + 32768 + 8388608);

  float* out = (float*)d_out;                     // FLOAT32 outputs
  float* XOUT = out;                              // 2*8*2048*64
  float* SPOUT = out + 2097152;                   // 8
  float* GOUT = out + 2097160;                    // 2*8*2048*2048
  float* AOUT = out + 69206024;                   // 2*8*2048*2048

  // f32 copies of qhat/skt in d_out's X region (scratch; kAttn overwrites X;
  // rewritten every call => graph-replay safe). Validated r16.
  float* QHATF = out;                             // 2 MB
  float* SKTF  = out + 524288;                    // 2 MB

  kS<<<8, 256, 0, stream>>>(emb, wsS, wsSP);
  kMLP<<<1024, 256, 0, stream>>>(Q, K, emb, W1, b1, W2, b2, W3, b3, wsS,
                                 QHAT, SKT, QHATF, SKTF);
  kSample<<<dim3(32, 16), 256, 0, stream>>>(noise, QHAT, SKT, QHATF, SKTF,
                                            wsSP, GB64, GOUT);
  kCvt<<<dim3(16, 16), 256, 0, stream>>>(K, V, KB, VT);   // overwrites QHAT/SKT
  kAttn<<<dim3(64, 16), 256, 0, stream>>>(Q, mask, KB, VT, GB32, XOUT, AOUT);
  kFin<<<1, 64, 0, stream>>>(wsSP, SPOUT);
}

// Round 18
// 461.600 us; speedup vs baseline: 1.3833x; 1.3833x over previous
//
#include <hip/hip_runtime.h>

// SBMAttention — round 18: kSample v5 (ILP-batched, f32 fast path, r12 grid).
// r17 DIRECTLY measured kSample: 384µs, 1.1 TB/s, VALU 11%, Occ 23% =>
// latency/MLP-bound, and effective BW tracks (waves in flight x per-thread
// outstanding loads). v5: 2048 blocks (r12 geometry, best known), f32 skv
// (32 VGPR; bit-exactness via margin + rare f64 fallback, validated r16/r17),
// 4 n-rows batched per iteration => 8 independent noise loads in flight.
// kAttn = r15 32-row (best). kMLP = r16 (writes f32 tables). Rest unchanged.

typedef float  f32x4 __attribute__((ext_vector_type(4)));
typedef float  f32x8 __attribute__((ext_vector_type(8)));
typedef double f64x2 __attribute__((ext_vector_type(2)));
typedef __bf16 bf16x8 __attribute__((ext_vector_type(8)));

__device__ __forceinline__ unsigned short f2bf(float f) {
  __bf16 b = (__bf16)f;
  return __builtin_bit_cast(unsigned short, b);
}
__device__ __forceinline__ float bf2f(unsigned short u) {
  return (float)__builtin_bit_cast(__bf16, u);
}

// ---------------- kS: cluster softmax (f64) — validated ----------------
__global__ __launch_bounds__(256) void kS(const float* __restrict__ emb,
                                          double* __restrict__ wsS,
                                          float* __restrict__ wsSP) {
  __shared__ double c[16][65];
  __shared__ double red[256];
  const int t = threadIdx.x, h = blockIdx.x;
  if (t == 0) wsSP[h] = 0.f;
  for (int i = t; i < 1024; i += 256) c[i >> 6][i & 63] = (double)emb[(size_t)h * 1024 + i];
  __syncthreads();
  const int k = t >> 4, j = t & 15;
  double acc = 0.0;
  for (int d = 0; d < 64; ++d) acc += c[k][d] * c[j][d];
  red[t] = acc; __syncthreads();
  for (int s = 128; s > 0; s >>= 1) { if (t < s) red[t] = fmax(red[t], red[t + s]); __syncthreads(); }
  const double mx = red[0]; __syncthreads();
  const double e = exp(acc - mx);
  red[t] = e; __syncthreads();
  for (int s = 128; s > 0; s >>= 1) { if (t < s) red[t] += red[t + s]; __syncthreads(); }
  wsS[h * 256 + t] = e / red[0];
}

// ---------------- kMLP: proj + hats (f64) + f32 copies (r16) ----------------
__global__ __launch_bounds__(256) void kMLP(
    const float* __restrict__ Q, const float* __restrict__ K,
    const float* __restrict__ emb,
    const float* __restrict__ W1, const float* __restrict__ b1,
    const float* __restrict__ W2, const float* __restrict__ b2,
    const float* __restrict__ W3, const float* __restrict__ b3,
    const double* __restrict__ wsS,
    double* __restrict__ QHAT, double* __restrict__ SKT,
    float* __restrict__ QHATF, float* __restrict__ SKTF) {
  __shared__ double Xt[64][66];
  __shared__ float  Wl[64][68];
  __shared__ float  bsS[64];
  __shared__ float  cl[16][68];
  __shared__ double kh[64][17];
  __shared__ double Sl[256];

  const int t = threadIdx.x;
  const int blk = blockIdx.x;
  const int side = blk >> 9;
  const int idx = blk & 511;
  const int bh = idx >> 5;
  const int h = bh & 7;
  const int chunk = idx & 31;
  const size_t t0 = (size_t)bh * 2048 + (size_t)chunk * 64;

  const float* src = side ? K : Q;
  for (int i = t; i < 4096; i += 256) Xt[i >> 6][i & 63] = (double)src[t0 * 64 + i];

  const float* Ws[3] = {W1, W2, W3};
  const float* bs[3] = {b1, b2, b3};
  const int te = t & 15, tt = t >> 4;
  const int e0 = te * 4, tok0 = tt * 4;

  for (int l = 0; l < 3; ++l) {
    __syncthreads();
    for (int i = t; i < 4096; i += 256) Wl[i >> 6][i & 63] = Ws[l][i];
    if (t < 64) bsS[t] = bs[l][t];
    __syncthreads();
    double o[4][4];
#pragma unroll
    for (int i = 0; i < 4; ++i)
#pragma unroll
      for (int j = 0; j < 4; ++j) o[i][j] = 0.0;
    for (int d = 0; d < 64; d += 4) {
      double xa[4][4];
#pragma unroll
      for (int i = 0; i < 4; ++i) {
        const f64x2 lo = *(const f64x2*)&Xt[tok0 + i][d];
        const f64x2 hi = *(const f64x2*)&Xt[tok0 + i][d + 2];
        xa[i][0] = lo[0]; xa[i][1] = lo[1]; xa[i][2] = hi[0]; xa[i][3] = hi[1];
      }
      float4 wb[4];
#pragma unroll
      for (int j = 0; j < 4; ++j) wb[j] = *(const float4*)&Wl[e0 + j][d];
#pragma unroll
      for (int dd = 0; dd < 4; ++dd) {     // d ascending: FMA order preserved
        const double w0 = (double)((dd == 0) ? wb[0].x : (dd == 1) ? wb[0].y : (dd == 2) ? wb[0].z : wb[0].w);
        const double w1 = (double)((dd == 0) ? wb[1].x : (dd == 1) ? wb[1].y : (dd == 2) ? wb[1].z : wb[1].w);
        const double w2 = (double)((dd == 0) ? wb[2].x : (dd == 1) ? wb[2].y : (dd == 2) ? wb[2].z : wb[2].w);
        const double w3 = (double)((dd == 0) ? wb[3].x : (dd == 1) ? wb[3].y : (dd == 2) ? wb[3].z : wb[3].w);
#pragma unroll
        for (int i = 0; i < 4; ++i) {
          const double xv = xa[i][dd];
          o[i][0] += xv * w0; o[i][1] += xv * w1; o[i][2] += xv * w2; o[i][3] += xv * w3;
        }
      }
    }
#pragma unroll
    for (int i = 0; i < 4; ++i)
#pragma unroll
      for (int j = 0; j < 4; ++j) {
        double v = o[i][j] + (double)bsS[e0 + j];
        if (l < 2) v = fmax(v, 0.0);
        o[i][j] = v;
      }
    __syncthreads();
#pragma unroll
    for (int i = 0; i < 4; ++i)
#pragma unroll
      for (int j = 0; j < 4; ++j) Xt[tok0 + i][e0 + j] = o[i][j];
  }
  __syncthreads();
  for (int i = t; i < 1024; i += 256) cl[i >> 6][i & 63] = emb[(size_t)h * 1024 + i];
  if (side) { for (int i = t; i < 256; i += 256) Sl[i] = wsS[h * 256 + i]; }
  __syncthreads();

  const int tok = t >> 2, k0 = (t & 3) * 4;
  double z[4] = {0.0, 0.0, 0.0, 0.0};
  for (int d = 0; d < 64; d += 2) {
    const f64x2 xv = *(const f64x2*)&Xt[tok][d];
    const float2 c0 = *(const float2*)&cl[k0 + 0][d];
    const float2 c1 = *(const float2*)&cl[k0 + 1][d];
    const float2 c2 = *(const float2*)&cl[k0 + 2][d];
    const float2 c3 = *(const float2*)&cl[k0 + 3][d];
    z[0] += xv[0] * (double)c0.x; z[1] += xv[0] * (double)c1.x;
    z[2] += xv[0] * (double)c2.x; z[3] += xv[0] * (double)c3.x;
    z[0] += xv[1] * (double)c0.y; z[1] += xv[1] * (double)c1.y;
    z[2] += xv[1] * (double)c2.y; z[3] += xv[1] * (double)c3.y;
  }
  double hat[4];
#pragma unroll
  for (int j = 0; j < 4; ++j) hat[j] = 1.0 / (1.0 + exp(-z[j]));

  if (!side) {
#pragma unroll
    for (int j = 0; j < 4; ++j) {
      QHAT[(t0 + tok) * 16 + k0 + j] = hat[j];
      QHATF[(t0 + tok) * 16 + k0 + j] = (float)hat[j];
    }
  } else {
    kh[tok][k0 + 0] = hat[0]; kh[tok][k0 + 1] = hat[1];
    kh[tok][k0 + 2] = hat[2]; kh[tok][k0 + 3] = hat[3];
    __syncthreads();
    double sk[4] = {0.0, 0.0, 0.0, 0.0};
    for (int jj = 0; jj < 16; ++jj) {
      const double kv = kh[tok][jj];
      sk[0] += Sl[(k0 + 0) * 16 + jj] * kv; sk[1] += Sl[(k0 + 1) * 16 + jj] * kv;
      sk[2] += Sl[(k0 + 2) * 16 + jj] * kv; sk[3] += Sl[(k0 + 3) * 16 + jj] * kv;
    }
#pragma unroll
    for (int j = 0; j < 4; ++j) {
      SKT[(t0 + tok) * 16 + k0 + j] = sk[j];
      SKTF[(t0 + tok) * 16 + k0 + j] = (float)sk[j];
    }
  }
}

// ---------------- kSample v5: ILP-batched, f32 fast path ----------------
// grid (16, 4, 16): nt (128-row tile? no: 64 rows, 4 at a time), mt, bh.
// Same geometry as r12: nt in x (32 tiles of 64 rows), mt in y, bh in z.
__global__ void kSample(
    const float* __restrict__ noise,
    const double* __restrict__ qhat, const double* __restrict__ skt,
    const float* __restrict__ qhatf, const float* __restrict__ sktf,
    float* __restrict__ wsSP,
    unsigned long long* __restrict__ GB64, float* __restrict__ GOUT) {
  const int t = threadIdx.x;
  const int lane = t & 63, wave = t >> 6;
  const int nt = blockIdx.x;
  const int mt = blockIdx.y;
  const int bh = blockIdx.z, h = bh & 7;
  const int n0 = nt * 64;
  const int mA = mt * 512 + wave * 64 + lane;
  const int mB = mA + 256;

  // f32 skt rows in registers (32 VGPR)
  float skvA[16], skvB[16];
  {
    const float* spA = sktf + ((size_t)bh * 2048 + mA) * 16;
    const float* spB = sktf + ((size_t)bh * 2048 + mB) * 16;
#pragma unroll
    for (int q = 0; q < 4; ++q) {
      *(f32x4*)(skvA + 4 * q) = *(const f32x4*)(spA + 4 * q);
      *(f32x4*)(skvB + 4 * q) = *(const f32x4*)(spB + 4 * q);
    }
  }

  const float* qbaseF = qhatf + ((size_t)bh * 2048 + n0) * 16;   // wave-uniform
  const double* qbase64 = qhat + ((size_t)bh * 2048 + n0) * 16;  // rare fallback
  const double* skA64 = skt + ((size_t)bh * 2048 + mA) * 16;
  const double* skB64 = skt + ((size_t)bh * 2048 + mB) * 16;
  const float* nzbase = noise + ((size_t)bh * 2048 + n0) * 2048;
  float* gobase = GOUT + ((size_t)bh * 2048 + n0) * 2048;
  unsigned long long* gbbase = GB64 + ((size_t)bh * 2048 + n0) * 32;
  const int gA = mA >> 6, gB = mB >> 6;

  int cnt = 0;
  for (int n4 = 0; n4 < 16; ++n4) {
    const int nb = n4 * 4;
    // ---- batch: 8 independent noise loads issued first ----
    float nzA[4], nzB[4];
#pragma unroll
    for (int r = 0; r < 4; ++r) {
      nzA[r] = nzbase[(size_t)(nb + r) * 2048 + mA];
      nzB[r] = nzbase[(size_t)(nb + r) * 2048 + mB];
    }
    // ---- 8 independent f32 dots ----
    float eaA[4], eaB[4];
#pragma unroll
    for (int r = 0; r < 4; ++r) {
      const float* qr = qbaseF + (size_t)(nb + r) * 16;   // uniform -> s_load
      float a = 0.f, b = 0.f;
#pragma unroll
      for (int k = 0; k < 16; ++k) {
        const float qk = qr[k];
        a = fmaf(qk, skvA[k], a);
        b = fmaf(qk, skvB[k], b);
      }
      eaA[r] = a; eaB[r] = b;
    }
    // ---- decisions + ballots + stores ----
#pragma unroll
    for (int r = 0; r < 4; ++r) {
      int g0, g1;
      if (__builtin_expect(fabsf(nzA[r] - eaA[r]) < 1e-5f, 0)) {
        const double* q64 = qbase64 + (size_t)(nb + r) * 16;
        double e = 0.0;
        for (int k = 0; k < 16; ++k) e += q64[k] * skA64[k];  // np order
        g0 = ((double)nzA[r] < e) ? 1 : 0;
      } else {
        g0 = (nzA[r] < eaA[r]) ? 1 : 0;
      }
      if (__builtin_expect(fabsf(nzB[r] - eaB[r]) < 1e-5f, 0)) {
        const double* q64 = qbase64 + (size_t)(nb + r) * 16;
        double e = 0.0;
        for (int k = 0; k < 16; ++k) e += q64[k] * skB64[k];
        g1 = ((double)nzB[r] < e) ? 1 : 0;
      } else {
        g1 = (nzB[r] < eaB[r]) ? 1 : 0;
      }
      cnt += g0 + g1;
      const unsigned long long b0 = __ballot(g0);
      const unsigned long long b1 = __ballot(g1);
      if (lane == 0) {
        gbbase[(size_t)(nb + r) * 32 + gA] = b0;
        gbbase[(size_t)(nb + r) * 32 + gB] = b1;
      }
      gobase[(size_t)(nb + r) * 2048 + mA] = g0 ? 1.0f : 0.0f;
      gobase[(size_t)(nb + r) * 2048 + mB] = g1 ? 1.0f : 0.0f;
    }
  }
  cnt += __shfl_xor(cnt, 1); cnt += __shfl_xor(cnt, 2); cnt += __shfl_xor(cnt, 4);
  cnt += __shfl_xor(cnt, 8); cnt += __shfl_xor(cnt, 16); cnt += __shfl_xor(cnt, 32);
  if (lane == 0) atomicAdd(&wsSP[h], (float)cnt);
}

// ---------------- kCvt: K->bf16 KB, V->bf16 transposed VT ----------------
__global__ __launch_bounds__(256) void kCvt(const float* __restrict__ K,
                                            const float* __restrict__ V,
                                            unsigned short* __restrict__ KB,
                                            unsigned short* __restrict__ VT) {
  __shared__ float vt[128][65];
  const int t = threadIdx.x;
  const int bh = blockIdx.x, ch = blockIdx.y;
  const size_t base = ((size_t)bh * 2048 + ch * 128) * 64;
  for (int i = t; i < 8192; i += 256) {
    KB[base + i] = f2bf(K[base + i]);
    vt[i >> 6][i & 63] = V[base + i];
  }
  __syncthreads();
  const size_t vbase = (size_t)bh * 64 * 2048 + ch * 128;
  for (int i = t; i < 8192; i += 256) {
    const int d = i >> 7, mm = i & 127;
    VT[vbase + (size_t)d * 2048 + mm] = f2bf(vt[mm][d]);
  }
}

// ---------------- kAttn: two-phase MFMA attention, 32-row Q-tiles (r15) -----
__global__ __launch_bounds__(256, 4) void kAttn(
    const float* __restrict__ Q, const int* __restrict__ maskp,
    const unsigned short* __restrict__ KB, const unsigned short* __restrict__ VT,
    const unsigned int* __restrict__ GB32,
    float* __restrict__ XOUT, float* __restrict__ AOUT) {
  __shared__ unsigned int bitsS[32][64];
  __shared__ unsigned short stageS[4][32][32];
  __shared__ float dredS[4][32];
  __shared__ float dinvS[32];
  __shared__ float xredS[32][68];

  const int t = threadIdx.x;
  const int wave = t >> 6, lane = t & 63;
  const int bh = blockIdx.y, b = bh >> 3;
  const int n0 = blockIdx.x * 32;
  const int hi2 = lane >> 4;
  const int hi8 = hi2 << 3;
  const int g4 = hi2 << 2;
  const int lm = lane & 15;

  for (int i = t; i < 2048; i += 256)
    bitsS[i >> 6][i & 63] = GB32[((size_t)bh * 2048 + n0 + (i >> 6)) * 64 + (i & 63)];
  for (int i = t; i < 32 * 68; i += 256) ((float*)xredS)[i] = 0.f;

  bf16x8 aq[2][2];
#pragma unroll
  for (int rs = 0; rs < 2; ++rs) {
    const float* qrow = Q + ((size_t)bh * 2048 + n0 + rs * 16 + lm) * 64;
#pragma unroll
    for (int hh = 0; hh < 2; ++hh) {
      const int d0 = hi8 + hh * 32;
      const f32x4 qa = *(const f32x4*)(qrow + d0);
      const f32x4 qb = *(const f32x4*)(qrow + d0 + 4);
      bf16x8 v;
      v[0] = (__bf16)qa[0]; v[1] = (__bf16)qa[1]; v[2] = (__bf16)qa[2]; v[3] = (__bf16)qa[3];
      v[4] = (__bf16)qb[0]; v[5] = (__bf16)qb[1]; v[6] = (__bf16)qb[2]; v[7] = (__bf16)qb[3];
      aq[rs][hh] = v;
    }
  }

  const unsigned short* kbp = KB + (size_t)bh * 2048 * 64;
  const unsigned short* vtp = VT + (size_t)bh * 64 * 2048;
  const int* mkp = maskp + b * 2048;
  __syncthreads();

  // PHASE 1: denominators
  float dsum[2][4];
#pragma unroll
  for (int rs = 0; rs < 2; ++rs)
#pragma unroll
    for (int r = 0; r < 4; ++r) dsum[rs][r] = 0.f;

  for (int it = 0; it < 16; ++it) {
    const int mb = (wave << 9) + (it << 5);
    f32x4 st[2][2];
#pragma unroll
    for (int tt = 0; tt < 2; ++tt) {
      const unsigned short* kr = kbp + (size_t)(mb + tt * 16 + lm) * 64 + hi8;
      const bf16x8 b0 = *(const bf16x8*)(kr);
      const bf16x8 b1 = *(const bf16x8*)(kr + 32);
#pragma unroll
      for (int rs = 0; rs < 2; ++rs) {
        f32x4 acc = (f32x4){0.f, 0.f, 0.f, 0.f};
        acc = __builtin_amdgcn_mfma_f32_16x16x32_bf16(aq[rs][0], b0, acc, 0, 0, 0);
        acc = __builtin_amdgcn_mfma_f32_16x16x32_bf16(aq[rs][1], b1, acc, 0, 0, 0);
        st[rs][tt] = acc;
      }
    }
#pragma unroll
    for (int tt = 0; tt < 2; ++tt) {
      const int mv = mkp[mb + tt * 16 + lm];
#pragma unroll
      for (int rs = 0; rs < 2; ++rs) {
        const f32x4 sv4 = st[rs][tt];
#pragma unroll
        for (int r = 0; r < 4; ++r) {
          const int g = (bitsS[rs * 16 + g4 + r][mb >> 5] >> (tt * 16 + lm)) & 1;
          if (g && !mv) dsum[rs][r] += __expf(sv4[r] * 0.125f);
        }
      }
    }
  }
#pragma unroll
  for (int rs = 0; rs < 2; ++rs)
#pragma unroll
    for (int r = 0; r < 4; ++r) {
      float v = dsum[rs][r];
      v += __shfl_xor(v, 1); v += __shfl_xor(v, 2); v += __shfl_xor(v, 4); v += __shfl_xor(v, 8);
      if (lm == 0) dredS[wave][rs * 16 + g4 + r] = v;
    }
  __syncthreads();
  if (t < 32) {
    const float dv = dredS[0][t] + dredS[1][t] + dredS[2][t] + dredS[3][t];
    dinvS[t] = 1.0f / fmaxf(dv, 1e-12f);
  }
  __syncthreads();

  // PHASE 2: u rebuild, PV, attn writes
  const size_t rowbase = (size_t)bh * 2048 + n0;
  f32x4 xacc[2][4];
#pragma unroll
  for (int rs = 0; rs < 2; ++rs)
#pragma unroll
    for (int td = 0; td < 4; ++td) xacc[rs][td] = (f32x4){0.f, 0.f, 0.f, 0.f};

  for (int it = 0; it < 16; ++it) {
    const int mb = (wave << 9) + (it << 5);
    f32x4 st[2][2];
#pragma unroll
    for (int tt = 0; tt < 2; ++tt) {
      const unsigned short* kr = kbp + (size_t)(mb + tt * 16 + lm) * 64 + hi8;
      const bf16x8 b0 = *(const bf16x8*)(kr);
      const bf16x8 b1 = *(const bf16x8*)(kr + 32);
#pragma unroll
      for (int rs = 0; rs < 2; ++rs) {
        f32x4 acc = (f32x4){0.f, 0.f, 0.f, 0.f};
        acc = __builtin_amdgcn_mfma_f32_16x16x32_bf16(aq[rs][0], b0, acc, 0, 0, 0);
        acc = __builtin_amdgcn_mfma_f32_16x16x32_bf16(aq[rs][1], b1, acc, 0, 0, 0);
        st[rs][tt] = acc;
      }
    }
#pragma unroll
    for (int tt = 0; tt < 2; ++tt) {
      const int mv = mkp[mb + tt * 16 + lm];
#pragma unroll
      for (int rs = 0; rs < 2; ++rs) {
        const f32x4 sv4 = st[rs][tt];
#pragma unroll
        for (int r = 0; r < 4; ++r) {
          const int row = rs * 16 + g4 + r;
          const int g = (bitsS[row][mb >> 5] >> (tt * 16 + lm)) & 1;
          const float u = (g && !mv) ? __expf(sv4[r] * 0.125f) : 0.f;
          const int col = tt * 16 + lm;
          stageS[wave][row][col ^ (((row >> 2) & 3) << 3)] = f2bf(u);
        }
      }
    }
    {
      const int rdcol = hi8 ^ (((lm >> 2) & 3) << 3);
      const bf16x8 ua0 = *(const bf16x8*)&stageS[wave][lm][rdcol];
      const bf16x8 ua1 = *(const bf16x8*)&stageS[wave][16 + lm][rdcol];
#pragma unroll
      for (int td = 0; td < 4; ++td) {
        const bf16x8 vb = *(const bf16x8*)(vtp + (size_t)(td * 16 + lm) * 2048 + mb + hi8);
        xacc[0][td] = __builtin_amdgcn_mfma_f32_16x16x32_bf16(ua0, vb, xacc[0][td], 0, 0, 0);
        xacc[1][td] = __builtin_amdgcn_mfma_f32_16x16x32_bf16(ua1, vb, xacc[1][td], 0, 0, 0);
      }
    }
#pragma unroll
    for (int rs = 0; rs < 2; ++rs) {
      const int row4 = lane >> 2, q = lane & 3;
      const int row = rs * 16 + row4;
      const int rc = (q * 8) ^ (((row4 >> 2) & 3) << 3);
      const unsigned short* up = &stageS[wave][row][rc];
      const float inv = dinvS[row];
      f32x8 av;
#pragma unroll
      for (int j = 0; j < 8; ++j) av[j] = bf2f(up[j]) * inv;
      *(f32x8*)(AOUT + (rowbase + row) * 2048 + mb + q * 8) = av;
    }
  }

  for (int w = 0; w < 4; ++w) {
    if (wave == w) {
#pragma unroll
      for (int rs = 0; rs < 2; ++rs)
#pragma unroll
        for (int td = 0; td < 4; ++td)
#pragma unroll
          for (int r = 0; r < 4; ++r)
            xredS[rs * 16 + g4 + r][td * 16 + lm] += xacc[rs][td][r];
    }
    __syncthreads();
  }
  for (int i = t; i < 2048; i += 256) {
    const int nl = i >> 6, d = i & 63;
    XOUT[(rowbase + nl) * 64 + d] = xredS[nl][d] * dinvS[nl];
  }
}

// ---------------- kFin: sparsity (f32) ----------------
__global__ void kFin(const float* __restrict__ wsSP, float* __restrict__ SPOUT) {
  const int t = threadIdx.x;
  if (t < 8) SPOUT[t] = wsSP[t] * (1.0f / 8388608.0f);  // /(2*2048*2048)
}

extern "C" void kernel_launch(void* const* d_in, const int* in_sizes, int n_in,
                              void* d_out, int out_size, void* d_ws, size_t ws_size,
                              hipStream_t stream) {
  const float* Q = (const float*)d_in[0];
  const float* K = (const float*)d_in[1];
  const float* V = (const float*)d_in[2];
  const int* mask = (const int*)d_in[3];
  const float* noise = (const float*)d_in[4];
  const float* emb = (const float*)d_in[5];
  const float* W1 = (const float*)d_in[6];
  const float* b1 = (const float*)d_in[7];
  const float* W2 = (const float*)d_in[8];
  const float* b2 = (const float*)d_in[9];
  const float* W3 = (const float*)d_in[10];
  const float* b3 = (const float*)d_in[11];

  char* ws = (char*)d_ws;
  double* wsS = (double*)(ws + 0);                          // 16 KB
  float* wsSP = (float*)(ws + 16384);                       // 8 f32
  double* QHAT = (double*)(ws + 32768);                     // 4 MB f64
  double* SKT  = (double*)(ws + 32768 + 4194304);           // 4 MB f64
  unsigned short* KB = (unsigned short*)(ws + 32768);             // 4 MB bf16
  unsigned short* VT = (unsigned short*)(ws + 32768 + 4194304);   // 4 MB bf16
  unsigned long long* GB64 = (unsigned long long*)(ws + 32768 + 8388608);  // 8 MB
  unsigned int* GB32 = (unsigned int*)(ws + 32768 + 8388608);

  float* out = (float*)d_out;                     // FLOAT32 outputs
  float* XOUT = out;                              // 2*8*2048*64
  float* SPOUT = out + 2097152;                   // 8
  float* GOUT = out + 2097160;                    // 2*8*2048*2048
  float* AOUT = out + 69206024;                   // 2*8*2048*2048

  // f32 tables in d_out's X region (scratch; kAttn overwrites X afterwards;
  // rewritten every call => graph-replay safe). Validated r16/r17.
  float* QHATF = out;                             // 2 MB
  float* SKTF  = out + 524288;                    // 2 MB

  kS<<<8, 256, 0, stream>>>(emb, wsS, wsSP);
  kMLP<<<1024, 256, 0, stream>>>(Q, K, emb, W1, b1, W2, b2, W3, b3, wsS,
                                 QHAT, SKT, QHATF, SKTF);
  kSample<<<dim3(32, 4, 16), 256, 0, stream>>>(noise, QHAT, SKT, QHATF, SKTF,
                                               wsSP, GB64, GOUT);
  kCvt<<<dim3(16, 16), 256, 0, stream>>>(K, V, KB, VT);   // overwrites QHAT/SKT
  kAttn<<<dim3(64, 16), 256, 0, stream>>>(Q, mask, KB, VT, GB32, XOUT, AOUT);
  kFin<<<1, 64, 0, stream>>>(wsSP, SPOUT);
}

// Round 19
// 444.624 us; speedup vs baseline: 1.4361x; 1.0382x over previous
//
#include <hip/hip_runtime.h>

// SBMAttention — round 19: kSample v6 (8-row ILP batch; 16 loads in flight).
// r18 confirmed kSample's regime: latency-bound, effective BW ~ waves x
// per-thread outstanding loads. v5 (4-row batch) gained 19µs; v6 doubles the
// batch. Everything else byte-identical to r18 (461.6µs best: kAttn r15
// 32-row, kMLP r16 f32-tables, f32+margin+f64-fallback sampling validated).

typedef float  f32x4 __attribute__((ext_vector_type(4)));
typedef float  f32x8 __attribute__((ext_vector_type(8)));
typedef double f64x2 __attribute__((ext_vector_type(2)));
typedef __bf16 bf16x8 __attribute__((ext_vector_type(8)));

__device__ __forceinline__ unsigned short f2bf(float f) {
  __bf16 b = (__bf16)f;
  return __builtin_bit_cast(unsigned short, b);
}
__device__ __forceinline__ float bf2f(unsigned short u) {
  return (float)__builtin_bit_cast(__bf16, u);
}

// ---------------- kS: cluster softmax (f64) — validated ----------------
__global__ __launch_bounds__(256) void kS(const float* __restrict__ emb,
                                          double* __restrict__ wsS,
                                          float* __restrict__ wsSP) {
  __shared__ double c[16][65];
  __shared__ double red[256];
  const int t = threadIdx.x, h = blockIdx.x;
  if (t == 0) wsSP[h] = 0.f;
  for (int i = t; i < 1024; i += 256) c[i >> 6][i & 63] = (double)emb[(size_t)h * 1024 + i];
  __syncthreads();
  const int k = t >> 4, j = t & 15;
  double acc = 0.0;
  for (int d = 0; d < 64; ++d) acc += c[k][d] * c[j][d];
  red[t] = acc; __syncthreads();
  for (int s = 128; s > 0; s >>= 1) { if (t < s) red[t] = fmax(red[t], red[t + s]); __syncthreads(); }
  const double mx = red[0]; __syncthreads();
  const double e = exp(acc - mx);
  red[t] = e; __syncthreads();
  for (int s = 128; s > 0; s >>= 1) { if (t < s) red[t] += red[t + s]; __syncthreads(); }
  wsS[h * 256 + t] = e / red[0];
}

// ---------------- kMLP: proj + hats (f64) + f32 copies (r16) ----------------
__global__ __launch_bounds__(256) void kMLP(
    const float* __restrict__ Q, const float* __restrict__ K,
    const float* __restrict__ emb,
    const float* __restrict__ W1, const float* __restrict__ b1,
    const float* __restrict__ W2, const float* __restrict__ b2,
    const float* __restrict__ W3, const float* __restrict__ b3,
    const double* __restrict__ wsS,
    double* __restrict__ QHAT, double* __restrict__ SKT,
    float* __restrict__ QHATF, float* __restrict__ SKTF) {
  __shared__ double Xt[64][66];
  __shared__ float  Wl[64][68];
  __shared__ float  bsS[64];
  __shared__ float  cl[16][68];
  __shared__ double kh[64][17];
  __shared__ double Sl[256];

  const int t = threadIdx.x;
  const int blk = blockIdx.x;
  const int side = blk >> 9;
  const int idx = blk & 511;
  const int bh = idx >> 5;
  const int h = bh & 7;
  const int chunk = idx & 31;
  const size_t t0 = (size_t)bh * 2048 + (size_t)chunk * 64;

  const float* src = side ? K : Q;
  for (int i = t; i < 4096; i += 256) Xt[i >> 6][i & 63] = (double)src[t0 * 64 + i];

  const float* Ws[3] = {W1, W2, W3};
  const float* bs[3] = {b1, b2, b3};
  const int te = t & 15, tt = t >> 4;
  const int e0 = te * 4, tok0 = tt * 4;

  for (int l = 0; l < 3; ++l) {
    __syncthreads();
    for (int i = t; i < 4096; i += 256) Wl[i >> 6][i & 63] = Ws[l][i];
    if (t < 64) bsS[t] = bs[l][t];
    __syncthreads();
    double o[4][4];
#pragma unroll
    for (int i = 0; i < 4; ++i)
#pragma unroll
      for (int j = 0; j < 4; ++j) o[i][j] = 0.0;
    for (int d = 0; d < 64; d += 4) {
      double xa[4][4];
#pragma unroll
      for (int i = 0; i < 4; ++i) {
        const f64x2 lo = *(const f64x2*)&Xt[tok0 + i][d];
        const f64x2 hi = *(const f64x2*)&Xt[tok0 + i][d + 2];
        xa[i][0] = lo[0]; xa[i][1] = lo[1]; xa[i][2] = hi[0]; xa[i][3] = hi[1];
      }
      float4 wb[4];
#pragma unroll
      for (int j = 0; j < 4; ++j) wb[j] = *(const float4*)&Wl[e0 + j][d];
#pragma unroll
      for (int dd = 0; dd < 4; ++dd) {     // d ascending: FMA order preserved
        const double w0 = (double)((dd == 0) ? wb[0].x : (dd == 1) ? wb[0].y : (dd == 2) ? wb[0].z : wb[0].w);
        const double w1 = (double)((dd == 0) ? wb[1].x : (dd == 1) ? wb[1].y : (dd == 2) ? wb[1].z : wb[1].w);
        const double w2 = (double)((dd == 0) ? wb[2].x : (dd == 1) ? wb[2].y : (dd == 2) ? wb[2].z : wb[2].w);
        const double w3 = (double)((dd == 0) ? wb[3].x : (dd == 1) ? wb[3].y : (dd == 2) ? wb[3].z : wb[3].w);
#pragma unroll
        for (int i = 0; i < 4; ++i) {
          const double xv = xa[i][dd];
          o[i][0] += xv * w0; o[i][1] += xv * w1; o[i][2] += xv * w2; o[i][3] += xv * w3;
        }
      }
    }
#pragma unroll
    for (int i = 0; i < 4; ++i)
#pragma unroll
      for (int j = 0; j < 4; ++j) {
        double v = o[i][j] + (double)bsS[e0 + j];
        if (l < 2) v = fmax(v, 0.0);
        o[i][j] = v;
      }
    __syncthreads();
#pragma unroll
    for (int i = 0; i < 4; ++i)
#pragma unroll
      for (int j = 0; j < 4; ++j) Xt[tok0 + i][e0 + j] = o[i][j];
  }
  __syncthreads();
  for (int i = t; i < 1024; i += 256) cl[i >> 6][i & 63] = emb[(size_t)h * 1024 + i];
  if (side) { for (int i = t; i < 256; i += 256) Sl[i] = wsS[h * 256 + i]; }
  __syncthreads();

  const int tok = t >> 2, k0 = (t & 3) * 4;
  double z[4] = {0.0, 0.0, 0.0, 0.0};
  for (int d = 0; d < 64; d += 2) {
    const f64x2 xv = *(const f64x2*)&Xt[tok][d];
    const float2 c0 = *(const float2*)&cl[k0 + 0][d];
    const float2 c1 = *(const float2*)&cl[k0 + 1][d];
    const float2 c2 = *(const float2*)&cl[k0 + 2][d];
    const float2 c3 = *(const float2*)&cl[k0 + 3][d];
    z[0] += xv[0] * (double)c0.x; z[1] += xv[0] * (double)c1.x;
    z[2] += xv[0] * (double)c2.x; z[3] += xv[0] * (double)c3.x;
    z[0] += xv[1] * (double)c0.y; z[1] += xv[1] * (double)c1.y;
    z[2] += xv[1] * (double)c2.y; z[3] += xv[1] * (double)c3.y;
  }
  double hat[4];
#pragma unroll
  for (int j = 0; j < 4; ++j) hat[j] = 1.0 / (1.0 + exp(-z[j]));

  if (!side) {
#pragma unroll
    for (int j = 0; j < 4; ++j) {
      QHAT[(t0 + tok) * 16 + k0 + j] = hat[j];
      QHATF[(t0 + tok) * 16 + k0 + j] = (float)hat[j];
    }
  } else {
    kh[tok][k0 + 0] = hat[0]; kh[tok][k0 + 1] = hat[1];
    kh[tok][k0 + 2] = hat[2]; kh[tok][k0 + 3] = hat[3];
    __syncthreads();
    double sk[4] = {0.0, 0.0, 0.0, 0.0};
    for (int jj = 0; jj < 16; ++jj) {
      const double kv = kh[tok][jj];
      sk[0] += Sl[(k0 + 0) * 16 + jj] * kv; sk[1] += Sl[(k0 + 1) * 16 + jj] * kv;
      sk[2] += Sl[(k0 + 2) * 16 + jj] * kv; sk[3] += Sl[(k0 + 3) * 16 + jj] * kv;
    }
#pragma unroll
    for (int j = 0; j < 4; ++j) {
      SKT[(t0 + tok) * 16 + k0 + j] = sk[j];
      SKTF[(t0 + tok) * 16 + k0 + j] = (float)sk[j];
    }
  }
}

// ---------------- kSample v6: 8-row ILP batch, f32 fast path ----------------
__global__ void kSample(
    const float* __restrict__ noise,
    const double* __restrict__ qhat, const double* __restrict__ skt,
    const float* __restrict__ qhatf, const float* __restrict__ sktf,
    float* __restrict__ wsSP,
    unsigned long long* __restrict__ GB64, float* __restrict__ GOUT) {
  const int t = threadIdx.x;
  const int lane = t & 63, wave = t >> 6;
  const int nt = blockIdx.x;
  const int mt = blockIdx.y;
  const int bh = blockIdx.z, h = bh & 7;
  const int n0 = nt * 64;
  const int mA = mt * 512 + wave * 64 + lane;
  const int mB = mA + 256;

  // f32 skt rows in registers (32 VGPR)
  float skvA[16], skvB[16];
  {
    const float* spA = sktf + ((size_t)bh * 2048 + mA) * 16;
    const float* spB = sktf + ((size_t)bh * 2048 + mB) * 16;
#pragma unroll
    for (int q = 0; q < 4; ++q) {
      *(f32x4*)(skvA + 4 * q) = *(const f32x4*)(spA + 4 * q);
      *(f32x4*)(skvB + 4 * q) = *(const f32x4*)(spB + 4 * q);
    }
  }

  const float* qbaseF = qhatf + ((size_t)bh * 2048 + n0) * 16;   // wave-uniform
  const double* qbase64 = qhat + ((size_t)bh * 2048 + n0) * 16;  // rare fallback
  const double* skA64 = skt + ((size_t)bh * 2048 + mA) * 16;
  const double* skB64 = skt + ((size_t)bh * 2048 + mB) * 16;
  const float* nzbase = noise + ((size_t)bh * 2048 + n0) * 2048;
  float* gobase = GOUT + ((size_t)bh * 2048 + n0) * 2048;
  unsigned long long* gbbase = GB64 + ((size_t)bh * 2048 + n0) * 32;
  const int gA = mA >> 6, gB = mB >> 6;

  int cnt = 0;
  for (int n8 = 0; n8 < 8; ++n8) {
    const int nb = n8 * 8;
    // ---- batch: 16 independent noise loads issued first ----
    float nzA[8], nzB[8];
#pragma unroll
    for (int r = 0; r < 8; ++r) {
      nzA[r] = nzbase[(size_t)(nb + r) * 2048 + mA];
      nzB[r] = nzbase[(size_t)(nb + r) * 2048 + mB];
    }
    // ---- 16 independent f32 dots (qr loads are wave-uniform -> scalar) ----
    float eaA[8], eaB[8];
#pragma unroll
    for (int r = 0; r < 8; ++r) {
      const float* qr = qbaseF + (size_t)(nb + r) * 16;
      float a = 0.f, b = 0.f;
#pragma unroll
      for (int k = 0; k < 16; ++k) {
        const float qk = qr[k];
        a = fmaf(qk, skvA[k], a);
        b = fmaf(qk, skvB[k], b);
      }
      eaA[r] = a; eaB[r] = b;
    }
    // ---- decisions + ballots + stores ----
#pragma unroll
    for (int r = 0; r < 8; ++r) {
      int g0, g1;
      if (__builtin_expect(fabsf(nzA[r] - eaA[r]) < 1e-5f, 0)) {
        const double* q64 = qbase64 + (size_t)(nb + r) * 16;
        double e = 0.0;
        for (int k = 0; k < 16; ++k) e += q64[k] * skA64[k];  // np order
        g0 = ((double)nzA[r] < e) ? 1 : 0;
      } else {
        g0 = (nzA[r] < eaA[r]) ? 1 : 0;
      }
      if (__builtin_expect(fabsf(nzB[r] - eaB[r]) < 1e-5f, 0)) {
        const double* q64 = qbase64 + (size_t)(nb + r) * 16;
        double e = 0.0;
        for (int k = 0; k < 16; ++k) e += q64[k] * skB64[k];
        g1 = ((double)nzB[r] < e) ? 1 : 0;
      } else {
        g1 = (nzB[r] < eaB[r]) ? 1 : 0;
      }
      cnt += g0 + g1;
      const unsigned long long b0 = __ballot(g0);
      const unsigned long long b1 = __ballot(g1);
      if (lane == 0) {
        gbbase[(size_t)(nb + r) * 32 + gA] = b0;
        gbbase[(size_t)(nb + r) * 32 + gB] = b1;
      }
      gobase[(size_t)(nb + r) * 2048 + mA] = g0 ? 1.0f : 0.0f;
      gobase[(size_t)(nb + r) * 2048 + mB] = g1 ? 1.0f : 0.0f;
    }
  }
  cnt += __shfl_xor(cnt, 1); cnt += __shfl_xor(cnt, 2); cnt += __shfl_xor(cnt, 4);
  cnt += __shfl_xor(cnt, 8); cnt += __shfl_xor(cnt, 16); cnt += __shfl_xor(cnt, 32);
  if (lane == 0) atomicAdd(&wsSP[h], (float)cnt);
}

// ---------------- kCvt: K->bf16 KB, V->bf16 transposed VT ----------------
__global__ __launch_bounds__(256) void kCvt(const float* __restrict__ K,
                                            const float* __restrict__ V,
                                            unsigned short* __restrict__ KB,
                                            unsigned short* __restrict__ VT) {
  __shared__ float vt[128][65];
  const int t = threadIdx.x;
  const int bh = blockIdx.x, ch = blockIdx.y;
  const size_t base = ((size_t)bh * 2048 + ch * 128) * 64;
  for (int i = t; i < 8192; i += 256) {
    KB[base + i] = f2bf(K[base + i]);
    vt[i >> 6][i & 63] = V[base + i];
  }
  __syncthreads();
  const size_t vbase = (size_t)bh * 64 * 2048 + ch * 128;
  for (int i = t; i < 8192; i += 256) {
    const int d = i >> 7, mm = i & 127;
    VT[vbase + (size_t)d * 2048 + mm] = f2bf(vt[mm][d]);
  }
}

// ---------------- kAttn: two-phase MFMA attention, 32-row Q-tiles (r15) -----
__global__ __launch_bounds__(256, 4) void kAttn(
    const float* __restrict__ Q, const int* __restrict__ maskp,
    const unsigned short* __restrict__ KB, const unsigned short* __restrict__ VT,
    const unsigned int* __restrict__ GB32,
    float* __restrict__ XOUT, float* __restrict__ AOUT) {
  __shared__ unsigned int bitsS[32][64];
  __shared__ unsigned short stageS[4][32][32];
  __shared__ float dredS[4][32];
  __shared__ float dinvS[32];
  __shared__ float xredS[32][68];

  const int t = threadIdx.x;
  const int wave = t >> 6, lane = t & 63;
  const int bh = blockIdx.y, b = bh >> 3;
  const int n0 = blockIdx.x * 32;
  const int hi2 = lane >> 4;
  const int hi8 = hi2 << 3;
  const int g4 = hi2 << 2;
  const int lm = lane & 15;

  for (int i = t; i < 2048; i += 256)
    bitsS[i >> 6][i & 63] = GB32[((size_t)bh * 2048 + n0 + (i >> 6)) * 64 + (i & 63)];
  for (int i = t; i < 32 * 68; i += 256) ((float*)xredS)[i] = 0.f;

  bf16x8 aq[2][2];
#pragma unroll
  for (int rs = 0; rs < 2; ++rs) {
    const float* qrow = Q + ((size_t)bh * 2048 + n0 + rs * 16 + lm) * 64;
#pragma unroll
    for (int hh = 0; hh < 2; ++hh) {
      const int d0 = hi8 + hh * 32;
      const f32x4 qa = *(const f32x4*)(qrow + d0);
      const f32x4 qb = *(const f32x4*)(qrow + d0 + 4);
      bf16x8 v;
      v[0] = (__bf16)qa[0]; v[1] = (__bf16)qa[1]; v[2] = (__bf16)qa[2]; v[3] = (__bf16)qa[3];
      v[4] = (__bf16)qb[0]; v[5] = (__bf16)qb[1]; v[6] = (__bf16)qb[2]; v[7] = (__bf16)qb[3];
      aq[rs][hh] = v;
    }
  }

  const unsigned short* kbp = KB + (size_t)bh * 2048 * 64;
  const unsigned short* vtp = VT + (size_t)bh * 64 * 2048;
  const int* mkp = maskp + b * 2048;
  __syncthreads();

  // PHASE 1: denominators
  float dsum[2][4];
#pragma unroll
  for (int rs = 0; rs < 2; ++rs)
#pragma unroll
    for (int r = 0; r < 4; ++r) dsum[rs][r] = 0.f;

  for (int it = 0; it < 16; ++it) {
    const int mb = (wave << 9) + (it << 5);
    f32x4 st[2][2];
#pragma unroll
    for (int tt = 0; tt < 2; ++tt) {
      const unsigned short* kr = kbp + (size_t)(mb + tt * 16 + lm) * 64 + hi8;
      const bf16x8 b0 = *(const bf16x8*)(kr);
      const bf16x8 b1 = *(const bf16x8*)(kr + 32);
#pragma unroll
      for (int rs = 0; rs < 2; ++rs) {
        f32x4 acc = (f32x4){0.f, 0.f, 0.f, 0.f};
        acc = __builtin_amdgcn_mfma_f32_16x16x32_bf16(aq[rs][0], b0, acc, 0, 0, 0);
        acc = __builtin_amdgcn_mfma_f32_16x16x32_bf16(aq[rs][1], b1, acc, 0, 0, 0);
        st[rs][tt] = acc;
      }
    }
#pragma unroll
    for (int tt = 0; tt < 2; ++tt) {
      const int mv = mkp[mb + tt * 16 + lm];
#pragma unroll
      for (int rs = 0; rs < 2; ++rs) {
        const f32x4 sv4 = st[rs][tt];
#pragma unroll
        for (int r = 0; r < 4; ++r) {
          const int g = (bitsS[rs * 16 + g4 + r][mb >> 5] >> (tt * 16 + lm)) & 1;
          if (g && !mv) dsum[rs][r] += __expf(sv4[r] * 0.125f);
        }
      }
    }
  }
#pragma unroll
  for (int rs = 0; rs < 2; ++rs)
#pragma unroll
    for (int r = 0; r < 4; ++r) {
      float v = dsum[rs][r];
      v += __shfl_xor(v, 1); v += __shfl_xor(v, 2); v += __shfl_xor(v, 4); v += __shfl_xor(v, 8);
      if (lm == 0) dredS[wave][rs * 16 + g4 + r] = v;
    }
  __syncthreads();
  if (t < 32) {
    const float dv = dredS[0][t] + dredS[1][t] + dredS[2][t] + dredS[3][t];
    dinvS[t] = 1.0f / fmaxf(dv, 1e-12f);
  }
  __syncthreads();

  // PHASE 2: u rebuild, PV, attn writes
  const size_t rowbase = (size_t)bh * 2048 + n0;
  f32x4 xacc[2][4];
#pragma unroll
  for (int rs = 0; rs < 2; ++rs)
#pragma unroll
    for (int td = 0; td < 4; ++td) xacc[rs][td] = (f32x4){0.f, 0.f, 0.f, 0.f};

  for (int it = 0; it < 16; ++it) {
    const int mb = (wave << 9) + (it << 5);
    f32x4 st[2][2];
#pragma unroll
    for (int tt = 0; tt < 2; ++tt) {
      const unsigned short* kr = kbp + (size_t)(mb + tt * 16 + lm) * 64 + hi8;
      const bf16x8 b0 = *(const bf16x8*)(kr);
      const bf16x8 b1 = *(const bf16x8*)(kr + 32);
#pragma unroll
      for (int rs = 0; rs < 2; ++rs) {
        f32x4 acc = (f32x4){0.f, 0.f, 0.f, 0.f};
        acc = __builtin_amdgcn_mfma_f32_16x16x32_bf16(aq[rs][0], b0, acc, 0, 0, 0);
        acc = __builtin_amdgcn_mfma_f32_16x16x32_bf16(aq[rs][1], b1, acc, 0, 0, 0);
        st[rs][tt] = acc;
      }
    }
#pragma unroll
    for (int tt = 0; tt < 2; ++tt) {
      const int mv = mkp[mb + tt * 16 + lm];
#pragma unroll
      for (int rs = 0; rs < 2; ++rs) {
        const f32x4 sv4 = st[rs][tt];
#pragma unroll
        for (int r = 0; r < 4; ++r) {
          const int row = rs * 16 + g4 + r;
          const int g = (bitsS[row][mb >> 5] >> (tt * 16 + lm)) & 1;
          const float u = (g && !mv) ? __expf(sv4[r] * 0.125f) : 0.f;
          const int col = tt * 16 + lm;
          stageS[wave][row][col ^ (((row >> 2) & 3) << 3)] = f2bf(u);
        }
      }
    }
    {
      const int rdcol = hi8 ^ (((lm >> 2) & 3) << 3);
      const bf16x8 ua0 = *(const bf16x8*)&stageS[wave][lm][rdcol];
      const bf16x8 ua1 = *(const bf16x8*)&stageS[wave][16 + lm][rdcol];
#pragma unroll
      for (int td = 0; td < 4; ++td) {
        const bf16x8 vb = *(const bf16x8*)(vtp + (size_t)(td * 16 + lm) * 2048 + mb + hi8);
        xacc[0][td] = __builtin_amdgcn_mfma_f32_16x16x32_bf16(ua0, vb, xacc[0][td], 0, 0, 0);
        xacc[1][td] = __builtin_amdgcn_mfma_f32_16x16x32_bf16(ua1, vb, xacc[1][td], 0, 0, 0);
      }
    }
#pragma unroll
    for (int rs = 0; rs < 2; ++rs) {
      const int row4 = lane >> 2, q = lane & 3;
      const int row = rs * 16 + row4;
      const int rc = (q * 8) ^ (((row4 >> 2) & 3) << 3);
      const unsigned short* up = &stageS[wave][row][rc];
      const float inv = dinvS[row];
      f32x8 av;
#pragma unroll
      for (int j = 0; j < 8; ++j) av[j] = bf2f(up[j]) * inv;
      *(f32x8*)(AOUT + (rowbase + row) * 2048 + mb + q * 8) = av;
    }
  }

  for (int w = 0; w < 4; ++w) {
    if (wave == w) {
#pragma unroll
      for (int rs = 0; rs < 2; ++rs)
#pragma unroll
        for (int td = 0; td < 4; ++td)
#pragma unroll
          for (int r = 0; r < 4; ++r)
            xredS[rs * 16 + g4 + r][td * 16 + lm] += xacc[rs][td][r];
    }
    __syncthreads();
  }
  for (int i = t; i < 2048; i += 256) {
    const int nl = i >> 6, d = i & 63;
    XOUT[(rowbase + nl) * 64 + d] = xredS[nl][d] * dinvS[nl];
  }
}

// ---------------- kFin: sparsity (f32) ----------------
__global__ void kFin(const float* __restrict__ wsSP, float* __restrict__ SPOUT) {
  const int t = threadIdx.x;
  if (t < 8) SPOUT[t] = wsSP[t] * (1.0f / 8388608.0f);  // /(2*2048*2048)
}

extern "C" void kernel_launch(void* const* d_in, const int* in_sizes, int n_in,
                              void* d_out, int out_size, void* d_ws, size_t ws_size,
                              hipStream_t stream) {
  const float* Q = (const float*)d_in[0];
  const float* K = (const float*)d_in[1];
  const float* V = (const float*)d_in[2];
  const int* mask = (const int*)d_in[3];
  const float* noise = (const float*)d_in[4];
  const float* emb = (const float*)d_in[5];
  const float* W1 = (const float*)d_in[6];
  const float* b1 = (const float*)d_in[7];
  const float* W2 = (const float*)d_in[8];
  const float* b2 = (const float*)d_in[9];
  const float* W3 = (const float*)d_in[10];
  const float* b3 = (const float*)d_in[11];

  char* ws = (char*)d_ws;
  double* wsS = (double*)(ws + 0);                          // 16 KB
  float* wsSP = (float*)(ws + 16384);                       // 8 f32
  double* QHAT = (double*)(ws + 32768);                     // 4 MB f64
  double* SKT  = (double*)(ws + 32768 + 4194304);           // 4 MB f64
  unsigned short* KB = (unsigned short*)(ws + 32768);             // 4 MB bf16
  unsigned short* VT = (unsigned short*)(ws + 32768 + 4194304);   // 4 MB bf16
  unsigned long long* GB64 = (unsigned long long*)(ws + 32768 + 8388608);  // 8 MB
  unsigned int* GB32 = (unsigned int*)(ws + 32768 + 8388608);

  float* out = (float*)d_out;                     // FLOAT32 outputs
  float* XOUT = out;                              // 2*8*2048*64
  float* SPOUT = out + 2097152;                   // 8
  float* GOUT = out + 2097160;                    // 2*8*2048*2048
  float* AOUT = out + 69206024;                   // 2*8*2048*2048

  // f32 tables in d_out's X region (scratch; kAttn overwrites X afterwards;
  // rewritten every call => graph-replay safe). Validated r16-r18.
  float* QHATF = out;                             // 2 MB
  float* SKTF  = out + 524288;                    // 2 MB

  kS<<<8, 256, 0, stream>>>(emb, wsS, wsSP);
  kMLP<<<1024, 256, 0, stream>>>(Q, K, emb, W1, b1, W2, b2, W3, b3, wsS,
                                 QHAT, SKT, QHATF, SKTF);
  kSample<<<dim3(32, 4, 16), 256, 0, stream>>>(noise, QHAT, SKT, QHATF, SKTF,
                                               wsSP, GB64, GOUT);
  kCvt<<<dim3(16, 16), 256, 0, stream>>>(K, V, KB, VT);   // overwrites QHAT/SKT
  kAttn<<<dim3(64, 16), 256, 0, stream>>>(Q, mask, KB, VT, GB32, XOUT, AOUT);
  kFin<<<1, 64, 0, stream>>>(wsSP, SPOUT);
}